// Round 9
// baseline (116.909 us; speedup 1.0000x reference)
//
#include <hip/hip_runtime.h>
#include <hip/hip_cooperative_groups.h>
#include <math.h>

namespace cg = cooperative_groups;

#define N 4096
#define MARGINF 2.0f
#define EPSF 1e-4f

typedef _Float16 f16x2 __attribute__((ext_vector_type(2)));  // native arithmetic type

__device__ __forceinline__ unsigned f2u(f16x2 h){ return __builtin_bit_cast(unsigned, h); }
__device__ __forceinline__ f16x2 u2f(unsigned u){ return __builtin_bit_cast(f16x2, u); }
__device__ __forceinline__ unsigned pku(float a, float b){
    return __builtin_bit_cast(unsigned, __builtin_amdgcn_cvt_pkrtz(a, b));
}
__device__ __forceinline__ f16x2 pk2(float a){ return u2f(pku(a, a)); }
__device__ __forceinline__ float fdot2(f16x2 a, f16x2 b, float c){
    return __builtin_amdgcn_fdot2(a, b, c, false);
}
__device__ __forceinline__ f16x2 c_one(){ return u2f(0x3C003C00u); }
__device__ __forceinline__ f16x2 c_two(){ return u2f(0x40004000u); }
__device__ __forceinline__ f16x2 c_zero(){ return u2f(0u); }
__device__ __forceinline__ f16x2 c_big(){ return u2f(0x7BFF7BFFu); } // 65504

constexpr int CC = 128;                        // columns per block (64 packed u32)
constexpr int NCHUNK = N / CC;                 // 32
constexpr int RTS = 1024;                      // score row-tile (4 rows/thread)
constexpr int RTP = 512;                       // pred row-tile (2 rows/thread)
constexpr int SCORE_PER_STREAM = 80;           // sum_{ti=0..3} (32 - 8*ti)
constexpr int NSCORE_BLK = 4 * SCORE_PER_STREAM;      // 320
constexpr int NPRED_BLK = (N / RTP) * NCHUNK;         // 256
constexpr int NBLK = NSCORE_BLK + NPRED_BLK;          // 576
constexpr int PRED_PART = 512;                 // ws float index of pred partials
constexpr int G16_BYTE_OFF = 4096;             // grad16 region (ushort[4096*32])

// ws layout, all pure-written every call:
//   float[0..319]    score triangle partials (i<j only)
//   float[512..767]  pred full-matrix partials
//   bytes [4096 .. 4096+262144)  fp16 grad partials, grad16[row*32 + chunk]

__device__ __forceinline__ void body2(unsigned lm2u, unsigned pm2u,
                                      f16x2 lk2, f16x2 rk2, float& acc){
    const f16x2 ld2 = u2f(lm2u) - lk2;
    const unsigned sgn = f2u(ld2) & 0x80008000u;
    const f16x2 pd2 = u2f(pm2u) - rk2;
    const f16x2 x2 = u2f(f2u(pd2) ^ sgn);
    const f16x2 m2 = __builtin_elementwise_max(c_two() - x2, c_zero());
    acc = fdot2(m2, c_one(), acc);
}

__device__ __forceinline__ void body2m(unsigned lm2u, unsigned pm2u,
                                       f16x2 lk2, f16x2 rk2, int d, float& acc){
    // d = (global col of low half) - (global row); include col iff col > row
    const f16x2 ld2 = u2f(lm2u) - lk2;
    const unsigned sgn = f2u(ld2) & 0x80008000u;
    const f16x2 pd2 = u2f(pm2u) - rk2;
    const f16x2 x2 = u2f(f2u(pd2) ^ sgn);
    const f16x2 m2 = __builtin_elementwise_max(c_two() - x2, c_zero());
    const unsigned mu = (d >= 0) ? ((d > 0) ? 0x3C003C00u : 0x3C000000u) : 0u;
    acc = fdot2(m2, u2f(mu), acc);
}

__device__ __forceinline__ void body2g(unsigned lm2u, unsigned pm2u,
                                       f16x2 lk2, f16x2 rk2, float& acc, float& gacc){
    const f16x2 ld2 = u2f(lm2u) - lk2;
    const unsigned sgn = f2u(ld2) & 0x80008000u;
    const f16x2 pd2 = u2f(pm2u) - rk2;
    const f16x2 x2 = u2f(f2u(pd2) ^ sgn);
    const f16x2 m2 = __builtin_elementwise_max(c_two() - x2, c_zero());
    acc = fdot2(m2, c_one(), acc);
    const f16x2 ind2 = __builtin_elementwise_min(m2 * c_big(), c_one());
    gacc = fdot2(u2f(f2u(ind2) ^ sgn), c_one(), gacc);   // +-indicator
}

// ---- shared device code: phase A (pair work) ----
__device__ __forceinline__ float pair_phase(
    const float* __restrict__ scores, const float* __restrict__ pred,
    const float* __restrict__ label, float* __restrict__ ws,
    unsigned* lab16, unsigned* col16, int bid, int tid, bool isScore)
{
    int ti, c, rb;
    const float* __restrict__ colsrc;
    if (isScore) {
        const int stream = bid / SCORE_PER_STREAM;
        const int b = bid % SCORE_PER_STREAM;
        if      (b < 32) { ti = 0; c = b; }
        else if (b < 56) { ti = 1; c = 8  + (b - 32); }
        else if (b < 72) { ti = 2; c = 16 + (b - 56); }
        else             { ti = 3; c = 24 + (b - 72); }
        rb = ti * RTS;
        colsrc = scores + stream * N;
    } else {
        const int q = bid - NSCORE_BLK;
        ti = q >> 5;             // pred row-tile 0..7
        c  = q & 31;
        rb = ti * RTP;
        colsrc = pred;
    }
    const int c0 = c * CC;

    if (tid < CC / 2) {
        const float2 lf = *(const float2*)&label[c0 + 2 * tid];
        lab16[tid] = pku(lf.x, lf.y);
    } else if (tid < CC) {
        const int q = tid - CC / 2;
        const float2 pf = *(const float2*)&colsrc[c0 + 2 * q];
        col16[q] = pku(pf.x, pf.y);
    }
    __syncthreads();

    float blocksum;

    if (isScore) {
        int r[4]; f16x2 rk2[4], lk2[4];
        #pragma unroll
        for (int k = 0; k < 4; ++k) {
            r[k] = rb + tid + 256 * k;
            rk2[k] = pk2(colsrc[r[k]]);
            lk2[k] = pk2(label[r[k]]);
        }
        float acc[8] = {0.f,0.f,0.f,0.f,0.f,0.f,0.f,0.f};

        if (c >= 8 * (ti + 1)) {
            #pragma unroll 4
            for (int q = 0; q < CC / 16; ++q) {
                const uint4 l4a = *(const uint4*)&lab16[q * 8];
                const uint4 s4a = *(const uint4*)&col16[q * 8];
                const uint4 l4b = *(const uint4*)&lab16[q * 8 + 4];
                const uint4 s4b = *(const uint4*)&col16[q * 8 + 4];
                #pragma unroll
                for (int k = 0; k < 4; ++k) {
                    body2(l4a.x, s4a.x, lk2[k], rk2[k], acc[k]);
                    body2(l4a.y, s4a.y, lk2[k], rk2[k], acc[4 + k]);
                    body2(l4a.z, s4a.z, lk2[k], rk2[k], acc[k]);
                    body2(l4a.w, s4a.w, lk2[k], rk2[k], acc[4 + k]);
                    body2(l4b.x, s4b.x, lk2[k], rk2[k], acc[k]);
                    body2(l4b.y, s4b.y, lk2[k], rk2[k], acc[4 + k]);
                    body2(l4b.z, s4b.z, lk2[k], rk2[k], acc[k]);
                    body2(l4b.w, s4b.w, lk2[k], rk2[k], acc[4 + k]);
                }
            }
        } else {
            #pragma unroll 4
            for (int q = 0; q < CC / 8; ++q) {
                const uint4 l4 = *(const uint4*)&lab16[q * 4];
                const uint4 s4 = *(const uint4*)&col16[q * 4];
                const int cb = c0 + q * 8;
                #pragma unroll
                for (int k = 0; k < 4; ++k) {
                    body2m(l4.x, s4.x, lk2[k], rk2[k], cb + 0 - r[k], acc[k]);
                    body2m(l4.y, s4.y, lk2[k], rk2[k], cb + 2 - r[k], acc[4 + k]);
                    body2m(l4.z, s4.z, lk2[k], rk2[k], cb + 4 - r[k], acc[k]);
                    body2m(l4.w, s4.w, lk2[k], rk2[k], cb + 6 - r[k], acc[4 + k]);
                }
            }
        }
        blocksum = (acc[0] + acc[1]) + (acc[2] + acc[3])
                 + (acc[4] + acc[5]) + (acc[6] + acc[7]);
    } else {
        int r[2]; f16x2 rk2[2], lk2[2];
        #pragma unroll
        for (int k = 0; k < 2; ++k) {
            r[k] = rb + tid + 256 * k;
            rk2[k] = pk2(pred[r[k]]);
            lk2[k] = pk2(label[r[k]]);
        }
        float acc[4] = {0.f,0.f,0.f,0.f};
        float grd[4] = {0.f,0.f,0.f,0.f};

        #pragma unroll 4
        for (int q = 0; q < CC / 8; ++q) {
            const uint4 l4 = *(const uint4*)&lab16[q * 4];
            const uint4 s4 = *(const uint4*)&col16[q * 4];
            #pragma unroll
            for (int k = 0; k < 2; ++k) {
                body2g(l4.x, s4.x, lk2[k], rk2[k], acc[k],     grd[k]);
                body2g(l4.y, s4.y, lk2[k], rk2[k], acc[2 + k], grd[2 + k]);
                body2g(l4.z, s4.z, lk2[k], rk2[k], acc[k],     grd[k]);
                body2g(l4.w, s4.w, lk2[k], rk2[k], acc[2 + k], grd[2 + k]);
            }
        }
        unsigned short* g16 = (unsigned short*)((char*)ws + G16_BYTE_OFF);
        #pragma unroll
        for (int k = 0; k < 2; ++k) {
            float g = grd[k] + grd[2 + k];
            if ((r[k] >> 7) == c) g -= 1.0f;   // ref: sign(0)=0 on diagonal
            const _Float16 gh = (_Float16)g;   // exact: |g| <= 128, integer
            g16[r[k] * NCHUNK + c] = __builtin_bit_cast(unsigned short, gh);
        }
        blocksum = (acc[0] + acc[1]) + (acc[2] + acc[3]);
    }
    return blocksum;
}

// ---- shared device code: finalize reduction (one block) ----
__device__ __forceinline__ void finalize_phase(
    const float* __restrict__ pred, const float* __restrict__ label,
    const float* __restrict__ ws, float* __restrict__ out,
    float* red, int tid)
{
    const unsigned short* g16r = (const unsigned short*)((const char*)ws + G16_BYTE_OFF);
    float sse = 0.f, g2sq = 0.f;
    #pragma unroll
    for (int k = 0; k < 16; ++k) {
        const int i = k * 256 + tid;
        const float d = pred[i] - label[i];
        sse += d * d;
        const uint4* gp = (const uint4*)(g16r + i * NCHUNK);   // 64B per row
        const uint4 a = gp[0], b = gp[1], cq = gp[2], e = gp[3];
        const f16x2 s0 = (u2f(a.x) + u2f(a.y)) + (u2f(a.z) + u2f(a.w));
        const f16x2 s1 = (u2f(b.x) + u2f(b.y)) + (u2f(b.z) + u2f(b.w));
        const f16x2 s2 = (u2f(cq.x) + u2f(cq.y)) + (u2f(cq.z) + u2f(cq.w));
        const f16x2 s3 = (u2f(e.x) + u2f(e.y)) + (u2f(e.z) + u2f(e.w));
        const f16x2 t0 = s0 + s1, t1 = s2 + s3;
        const float g = ((float)t0.x + (float)t0.y) + ((float)t1.x + (float)t1.y);
        g2sq += g * g;
    }

    float br = ws[tid] + ((tid < 64) ? ws[256 + tid] : 0.f);   // 320 score partials
    float pr = ws[PRED_PART + tid];                             // 256 pred partials

    #pragma unroll
    for (int off = 32; off > 0; off >>= 1) {
        sse  += __shfl_xor(sse,  off, 64);
        g2sq += __shfl_xor(g2sq, off, 64);
        br   += __shfl_xor(br,   off, 64);
        pr   += __shfl_xor(pr,   off, 64);
    }
    const int wid = tid >> 6;
    const int lane = tid & 63;
    if (lane == 0) {
        red[wid] = sse; red[4 + wid] = g2sq;
        red[8 + wid] = br; red[12 + wid] = pr;
    }
    __syncthreads();
    if (tid == 0) {
        const float sseT  = red[0] + red[1] + red[2] + red[3];
        const float g2sqT = red[4] + red[5] + red[6] + red[7];
        const float brT   = red[8] + red[9] + red[10] + red[11];   // i<j only
        const float prT   = red[12] + red[13] + red[14] + red[15]; // full matrix
        const float rankp = (prT - (float)N * MARGINF) * 0.5f;
        const float mse = sseT / (float)N;
        const float g1 = (2.0f / (float)N) * sqrtf(sseT);
        const float g2 = sqrtf(g2sqT);
        const float beta = g1 / (g2 + EPSF);
        out[0] = 0.25f * brT + mse + beta * rankp;
    }
}

// ---- cooperative single-node kernel ----
__global__ __launch_bounds__(256, 4) void fused_kernel(
    const float* __restrict__ scores, const float* __restrict__ pred,
    const float* __restrict__ label, float* __restrict__ ws,
    float* __restrict__ out)
{
    __shared__ unsigned lab16[CC / 2];
    __shared__ unsigned col16[CC / 2];
    __shared__ float red[16];

    const int bid = blockIdx.x;
    const int tid = threadIdx.x;
    const bool isScore = (bid < NSCORE_BLK);

    float blocksum = pair_phase(scores, pred, label, ws, lab16, col16, bid, tid, isScore);

    #pragma unroll
    for (int off = 32; off > 0; off >>= 1)
        blocksum += __shfl_xor(blocksum, off, 64);
    {
        const int wid = tid >> 6;
        const int lane = tid & 63;
        if (lane == 0) red[wid] = blocksum;
        __syncthreads();
        if (tid == 0) {
            const float total = red[0] + red[1] + red[2] + red[3];
            if (isScore) ws[bid] = total;
            else         ws[PRED_PART + (bid - NSCORE_BLK)] = total;
        }
    }

    cg::this_grid().sync();
    if (bid != 0) return;
    __syncthreads();   // red[] reuse safety
    finalize_phase(pred, label, ws, out, red, tid);
}

// ---- fallback two-kernel path (proven R7) ----
__global__ __launch_bounds__(256) void pair_kernel(
    const float* __restrict__ scores, const float* __restrict__ pred,
    const float* __restrict__ label, float* __restrict__ ws)
{
    __shared__ unsigned lab16[CC / 2];
    __shared__ unsigned col16[CC / 2];
    __shared__ float red[4];

    const int bid = blockIdx.x;
    const int tid = threadIdx.x;
    const bool isScore = (bid < NSCORE_BLK);

    float blocksum = pair_phase(scores, pred, label, ws, lab16, col16, bid, tid, isScore);

    #pragma unroll
    for (int off = 32; off > 0; off >>= 1)
        blocksum += __shfl_xor(blocksum, off, 64);
    const int wid = tid >> 6;
    const int lane = tid & 63;
    if (lane == 0) red[wid] = blocksum;
    __syncthreads();
    if (tid == 0) {
        const float total = red[0] + red[1] + red[2] + red[3];
        if (isScore) ws[bid] = total;
        else         ws[PRED_PART + (bid - NSCORE_BLK)] = total;
    }
}

__global__ __launch_bounds__(256) void finalize_kernel(
    const float* __restrict__ pred, const float* __restrict__ label,
    const float* __restrict__ ws, float* __restrict__ out)
{
    __shared__ float red[16];
    finalize_phase(pred, label, ws, out, red, threadIdx.x);
}

extern "C" void kernel_launch(void* const* d_in, const int* in_sizes, int n_in,
                              void* d_out, int out_size, void* d_ws, size_t ws_size,
                              hipStream_t stream) {
    const float* scores = (const float*)d_in[0];
    const float* pred   = (const float*)d_in[1];
    const float* label  = (const float*)d_in[2];
    float* ws  = (float*)d_ws;
    float* out = (float*)d_out;

    void* kargs[] = {(void*)&scores, (void*)&pred, (void*)&label,
                     (void*)&ws, (void*)&out};
    hipError_t err = hipLaunchCooperativeKernel((const void*)fused_kernel,
                                                dim3(NBLK), dim3(256),
                                                kargs, 0, stream);
    if (err != hipSuccess) {
        (void)hipGetLastError();   // clear sticky error, take the 2-node path
        pair_kernel<<<NBLK, 256, 0, stream>>>(scores, pred, label, ws);
        finalize_kernel<<<1, 256, 0, stream>>>(pred, label, ws, out);
    }
}

// Round 10
// 76.088 us; speedup vs baseline: 1.5365x; 1.5365x over previous
//
#include <hip/hip_runtime.h>
#include <math.h>

#define N 4096
#define MARGINF 2.0f
#define EPSF 1e-4f

typedef _Float16 f16x2 __attribute__((ext_vector_type(2)));  // native arithmetic type

__device__ __forceinline__ unsigned f2u(f16x2 h){ return __builtin_bit_cast(unsigned, h); }
__device__ __forceinline__ f16x2 u2f(unsigned u){ return __builtin_bit_cast(f16x2, u); }
__device__ __forceinline__ unsigned pku(float a, float b){
    return __builtin_bit_cast(unsigned, __builtin_amdgcn_cvt_pkrtz(a, b));
}
__device__ __forceinline__ f16x2 pk2(float a){ return u2f(pku(a, a)); }
__device__ __forceinline__ float fdot2(f16x2 a, f16x2 b, float c){
    return __builtin_amdgcn_fdot2(a, b, c, false);
}
__device__ __forceinline__ f16x2 c_one(){ return u2f(0x3C003C00u); }
__device__ __forceinline__ f16x2 c_two(){ return u2f(0x40004000u); }
__device__ __forceinline__ f16x2 c_zero(){ return u2f(0u); }
__device__ __forceinline__ f16x2 c_big(){ return u2f(0x7BFF7BFFu); } // 65504

constexpr int CC = 128;                        // columns per block (64 packed u32)
constexpr int NCHUNK = N / CC;                 // 32
constexpr int RTS = 1024;                      // score row-tile (4 rows/thread)
constexpr int RTP = 512;                       // pred row-tile (2 rows/thread)
constexpr int SCORE_PER_STREAM = 80;           // sum_{ti=0..3} (32 - 8*ti)
constexpr int NSCORE_BLK = 4 * SCORE_PER_STREAM;      // 320
constexpr int NPRED_BLK = (N / RTP) * NCHUNK;         // 256
constexpr int NBLK = NSCORE_BLK + NPRED_BLK;          // 576
constexpr int PRED_PART = 512;                 // ws float index of pred partials
constexpr unsigned DONE_TAG = 0x3FA0B7C4u;     // != 0, != 0xAAAAAAAA poison
constexpr int TAG_BYTE_OFF = 8192;             // unsigned tags[NBLK]
constexpr int G16_BYTE_OFF = 16384;            // grad16 region (ushort[4096*32])

// ws layout, all pure-written every call:
//   float[0..319]     score triangle partials (i<j only)
//   float[512..767]   pred full-matrix partials
//   bytes [8192..)    done tags (reset to 0 by finalizer each call)
//   bytes [16384..)   fp16 grad partials, grad16[row*32 + chunk]

__device__ __forceinline__ void body2(unsigned lm2u, unsigned pm2u,
                                      f16x2 lk2, f16x2 rk2, float& acc){
    const f16x2 ld2 = u2f(lm2u) - lk2;
    const unsigned sgn = f2u(ld2) & 0x80008000u;
    const f16x2 pd2 = u2f(pm2u) - rk2;
    const f16x2 x2 = u2f(f2u(pd2) ^ sgn);
    const f16x2 m2 = __builtin_elementwise_max(c_two() - x2, c_zero());
    acc = fdot2(m2, c_one(), acc);
}

__device__ __forceinline__ void body2m(unsigned lm2u, unsigned pm2u,
                                       f16x2 lk2, f16x2 rk2, int d, float& acc){
    // d = (global col of low half) - (global row); include col iff col > row
    const f16x2 ld2 = u2f(lm2u) - lk2;
    const unsigned sgn = f2u(ld2) & 0x80008000u;
    const f16x2 pd2 = u2f(pm2u) - rk2;
    const f16x2 x2 = u2f(f2u(pd2) ^ sgn);
    const f16x2 m2 = __builtin_elementwise_max(c_two() - x2, c_zero());
    const unsigned mu = (d >= 0) ? ((d > 0) ? 0x3C003C00u : 0x3C000000u) : 0u;
    acc = fdot2(m2, u2f(mu), acc);
}

__device__ __forceinline__ void body2g(unsigned lm2u, unsigned pm2u,
                                       f16x2 lk2, f16x2 rk2, float& acc, float& gacc){
    const f16x2 ld2 = u2f(lm2u) - lk2;
    const unsigned sgn = f2u(ld2) & 0x80008000u;
    const f16x2 pd2 = u2f(pm2u) - rk2;
    const f16x2 x2 = u2f(f2u(pd2) ^ sgn);
    const f16x2 m2 = __builtin_elementwise_max(c_two() - x2, c_zero());
    acc = fdot2(m2, c_one(), acc);
    const f16x2 ind2 = __builtin_elementwise_min(m2 * c_big(), c_one());
    gacc = fdot2(u2f(f2u(ind2) ^ sgn), c_one(), gacc);   // +-indicator
}

// ---- phase A: pair work (identical to R7) ----
__device__ __forceinline__ float pair_phase(
    const float* __restrict__ scores, const float* __restrict__ pred,
    const float* __restrict__ label, float* __restrict__ ws,
    unsigned* lab16, unsigned* col16, int bid, int tid, bool isScore)
{
    int ti, c, rb;
    const float* __restrict__ colsrc;
    if (isScore) {
        const int stream = bid / SCORE_PER_STREAM;
        const int b = bid % SCORE_PER_STREAM;
        if      (b < 32) { ti = 0; c = b; }
        else if (b < 56) { ti = 1; c = 8  + (b - 32); }
        else if (b < 72) { ti = 2; c = 16 + (b - 56); }
        else             { ti = 3; c = 24 + (b - 72); }
        rb = ti * RTS;
        colsrc = scores + stream * N;
    } else {
        const int q = bid - NSCORE_BLK;
        ti = q >> 5;             // pred row-tile 0..7
        c  = q & 31;
        rb = ti * RTP;
        colsrc = pred;
    }
    const int c0 = c * CC;

    if (tid < CC / 2) {
        const float2 lf = *(const float2*)&label[c0 + 2 * tid];
        lab16[tid] = pku(lf.x, lf.y);
    } else if (tid < CC) {
        const int q = tid - CC / 2;
        const float2 pf = *(const float2*)&colsrc[c0 + 2 * q];
        col16[q] = pku(pf.x, pf.y);
    }
    __syncthreads();

    float blocksum;

    if (isScore) {
        int r[4]; f16x2 rk2[4], lk2[4];
        #pragma unroll
        for (int k = 0; k < 4; ++k) {
            r[k] = rb + tid + 256 * k;
            rk2[k] = pk2(colsrc[r[k]]);
            lk2[k] = pk2(label[r[k]]);
        }
        float acc[8] = {0.f,0.f,0.f,0.f,0.f,0.f,0.f,0.f};

        if (c >= 8 * (ti + 1)) {
            #pragma unroll 4
            for (int q = 0; q < CC / 16; ++q) {
                const uint4 l4a = *(const uint4*)&lab16[q * 8];
                const uint4 s4a = *(const uint4*)&col16[q * 8];
                const uint4 l4b = *(const uint4*)&lab16[q * 8 + 4];
                const uint4 s4b = *(const uint4*)&col16[q * 8 + 4];
                #pragma unroll
                for (int k = 0; k < 4; ++k) {
                    body2(l4a.x, s4a.x, lk2[k], rk2[k], acc[k]);
                    body2(l4a.y, s4a.y, lk2[k], rk2[k], acc[4 + k]);
                    body2(l4a.z, s4a.z, lk2[k], rk2[k], acc[k]);
                    body2(l4a.w, s4a.w, lk2[k], rk2[k], acc[4 + k]);
                    body2(l4b.x, s4b.x, lk2[k], rk2[k], acc[k]);
                    body2(l4b.y, s4b.y, lk2[k], rk2[k], acc[4 + k]);
                    body2(l4b.z, s4b.z, lk2[k], rk2[k], acc[k]);
                    body2(l4b.w, s4b.w, lk2[k], rk2[k], acc[4 + k]);
                }
            }
        } else {
            #pragma unroll 4
            for (int q = 0; q < CC / 8; ++q) {
                const uint4 l4 = *(const uint4*)&lab16[q * 4];
                const uint4 s4 = *(const uint4*)&col16[q * 4];
                const int cb = c0 + q * 8;
                #pragma unroll
                for (int k = 0; k < 4; ++k) {
                    body2m(l4.x, s4.x, lk2[k], rk2[k], cb + 0 - r[k], acc[k]);
                    body2m(l4.y, s4.y, lk2[k], rk2[k], cb + 2 - r[k], acc[4 + k]);
                    body2m(l4.z, s4.z, lk2[k], rk2[k], cb + 4 - r[k], acc[k]);
                    body2m(l4.w, s4.w, lk2[k], rk2[k], cb + 6 - r[k], acc[4 + k]);
                }
            }
        }
        blocksum = (acc[0] + acc[1]) + (acc[2] + acc[3])
                 + (acc[4] + acc[5]) + (acc[6] + acc[7]);
    } else {
        int r[2]; f16x2 rk2[2], lk2[2];
        #pragma unroll
        for (int k = 0; k < 2; ++k) {
            r[k] = rb + tid + 256 * k;
            rk2[k] = pk2(pred[r[k]]);
            lk2[k] = pk2(label[r[k]]);
        }
        float acc[4] = {0.f,0.f,0.f,0.f};
        float grd[4] = {0.f,0.f,0.f,0.f};

        #pragma unroll 4
        for (int q = 0; q < CC / 8; ++q) {
            const uint4 l4 = *(const uint4*)&lab16[q * 4];
            const uint4 s4 = *(const uint4*)&col16[q * 4];
            #pragma unroll
            for (int k = 0; k < 2; ++k) {
                body2g(l4.x, s4.x, lk2[k], rk2[k], acc[k],     grd[k]);
                body2g(l4.y, s4.y, lk2[k], rk2[k], acc[2 + k], grd[2 + k]);
                body2g(l4.z, s4.z, lk2[k], rk2[k], acc[k],     grd[k]);
                body2g(l4.w, s4.w, lk2[k], rk2[k], acc[2 + k], grd[2 + k]);
            }
        }
        unsigned short* g16 = (unsigned short*)((char*)ws + G16_BYTE_OFF);
        #pragma unroll
        for (int k = 0; k < 2; ++k) {
            float g = grd[k] + grd[2 + k];
            if ((r[k] >> 7) == c) g -= 1.0f;   // ref: sign(0)=0 on diagonal
            const _Float16 gh = (_Float16)g;   // exact: |g| <= 128, integer
            g16[r[k] * NCHUNK + c] = __builtin_bit_cast(unsigned short, gh);
        }
        blocksum = (acc[0] + acc[1]) + (acc[2] + acc[3]);
    }
    return blocksum;
}

// ---- finalize reduction (one block, identical to R7) ----
__device__ __forceinline__ void finalize_phase(
    const float* __restrict__ pred, const float* __restrict__ label,
    const float* __restrict__ ws, float* __restrict__ out,
    float* red, int tid)
{
    const unsigned short* g16r = (const unsigned short*)((const char*)ws + G16_BYTE_OFF);
    float sse = 0.f, g2sq = 0.f;
    #pragma unroll
    for (int k = 0; k < 16; ++k) {
        const int i = k * 256 + tid;
        const float d = pred[i] - label[i];
        sse += d * d;
        const uint4* gp = (const uint4*)(g16r + i * NCHUNK);   // 64B per row
        const uint4 a = gp[0], b = gp[1], cq = gp[2], e = gp[3];
        const f16x2 s0 = (u2f(a.x) + u2f(a.y)) + (u2f(a.z) + u2f(a.w));
        const f16x2 s1 = (u2f(b.x) + u2f(b.y)) + (u2f(b.z) + u2f(b.w));
        const f16x2 s2 = (u2f(cq.x) + u2f(cq.y)) + (u2f(cq.z) + u2f(cq.w));
        const f16x2 s3 = (u2f(e.x) + u2f(e.y)) + (u2f(e.z) + u2f(e.w));
        const f16x2 t0 = s0 + s1, t1 = s2 + s3;
        const float g = ((float)t0.x + (float)t0.y) + ((float)t1.x + (float)t1.y);
        g2sq += g * g;
    }

    float br = ws[tid] + ((tid < 64) ? ws[256 + tid] : 0.f);   // 320 score partials
    float pr = ws[PRED_PART + tid];                             // 256 pred partials

    #pragma unroll
    for (int off = 32; off > 0; off >>= 1) {
        sse  += __shfl_xor(sse,  off, 64);
        g2sq += __shfl_xor(g2sq, off, 64);
        br   += __shfl_xor(br,   off, 64);
        pr   += __shfl_xor(pr,   off, 64);
    }
    const int wid = tid >> 6;
    const int lane = tid & 63;
    if (lane == 0) {
        red[wid] = sse; red[4 + wid] = g2sq;
        red[8 + wid] = br; red[12 + wid] = pr;
    }
    __syncthreads();
    if (tid == 0) {
        const float sseT  = red[0] + red[1] + red[2] + red[3];
        const float g2sqT = red[4] + red[5] + red[6] + red[7];
        const float brT   = red[8] + red[9] + red[10] + red[11];   // i<j only
        const float prT   = red[12] + red[13] + red[14] + red[15]; // full matrix
        const float rankp = (prT - (float)N * MARGINF) * 0.5f;
        const float mse = sseT / (float)N;
        const float g1 = (2.0f / (float)N) * sqrtf(sseT);
        const float g2 = sqrtf(g2sqT);
        const float beta = g1 / (g2 + EPSF);
        out[0] = 0.25f * brT + mse + beta * rankp;
    }
}

// ---- single-node kernel: 576 pair blocks + 1 finalizer block ----
__global__ __launch_bounds__(256) void fused_kernel(
    const float* __restrict__ scores, const float* __restrict__ pred,
    const float* __restrict__ label, float* __restrict__ ws,
    float* __restrict__ out)
{
    __shared__ unsigned lab16[CC / 2];
    __shared__ unsigned col16[CC / 2];
    __shared__ float red[16];

    const int bid = blockIdx.x;
    const int tid = threadIdx.x;
    unsigned* tags = (unsigned*)((char*)ws + TAG_BYTE_OFF);

    if (bid < NBLK) {
        // ---- producer block ----
        const bool isScore = (bid < NSCORE_BLK);
        float blocksum = pair_phase(scores, pred, label, ws, lab16, col16,
                                    bid, tid, isScore);
        #pragma unroll
        for (int off = 32; off > 0; off >>= 1)
            blocksum += __shfl_xor(blocksum, off, 64);
        const int wid = tid >> 6;
        const int lane = tid & 63;
        if (lane == 0) red[wid] = blocksum;
        __syncthreads();
        if (tid == 0) {
            const float total = red[0] + red[1] + red[2] + red[3];
            if (isScore) ws[bid] = total;
            else         ws[PRED_PART + (bid - NSCORE_BLK)] = total;
        }
        // release: all this block's global stores, then tag
        __threadfence();
        __syncthreads();
        if (tid == 0)
            __hip_atomic_store(&tags[bid], DONE_TAG, __ATOMIC_RELEASE,
                               __HIP_MEMORY_SCOPE_AGENT);
        return;
    }

    // ---- finalizer block (bid == NBLK): spin on tags, reduce, reset ----
    for (int i = tid; i < NBLK; i += 256) {
        while (__hip_atomic_load(&tags[i], __ATOMIC_ACQUIRE,
                                 __HIP_MEMORY_SCOPE_AGENT) != DONE_TAG) {
            __builtin_amdgcn_s_sleep(2);
        }
    }
    __syncthreads();
    __threadfence();
    finalize_phase(pred, label, ws, out, red, tid);
    __syncthreads();
    // reset tags so the next replay starts clean
    for (int i = tid; i < NBLK; i += 256)
        __hip_atomic_store(&tags[i], 0u, __ATOMIC_RELAXED,
                           __HIP_MEMORY_SCOPE_AGENT);
}

extern "C" void kernel_launch(void* const* d_in, const int* in_sizes, int n_in,
                              void* d_out, int out_size, void* d_ws, size_t ws_size,
                              hipStream_t stream) {
    const float* scores = (const float*)d_in[0];
    const float* pred   = (const float*)d_in[1];
    const float* label  = (const float*)d_in[2];
    float* ws  = (float*)d_ws;
    float* out = (float*)d_out;

    fused_kernel<<<NBLK + 1, 256, 0, stream>>>(scores, pred, label, ws, out);
}

// Round 11
// 20.103 us; speedup vs baseline: 5.8156x; 3.7850x over previous
//
#include <hip/hip_runtime.h>
#include <math.h>

#define N 4096
#define MARGINF 2.0f
#define EPSF 1e-4f
#define SCOPE_AGENT __HIP_MEMORY_SCOPE_AGENT

typedef _Float16 f16x2 __attribute__((ext_vector_type(2)));  // native arithmetic type

__device__ __forceinline__ unsigned f2u(f16x2 h){ return __builtin_bit_cast(unsigned, h); }
__device__ __forceinline__ f16x2 u2f(unsigned u){ return __builtin_bit_cast(f16x2, u); }
__device__ __forceinline__ unsigned pku(float a, float b){
    return __builtin_bit_cast(unsigned, __builtin_amdgcn_cvt_pkrtz(a, b));
}
__device__ __forceinline__ f16x2 pk2(float a){ return u2f(pku(a, a)); }
__device__ __forceinline__ float fdot2(f16x2 a, f16x2 b, float c){
    return __builtin_amdgcn_fdot2(a, b, c, false);
}
__device__ __forceinline__ f16x2 c_one(){ return u2f(0x3C003C00u); }
__device__ __forceinline__ f16x2 c_two(){ return u2f(0x40004000u); }
__device__ __forceinline__ f16x2 c_zero(){ return u2f(0u); }
__device__ __forceinline__ f16x2 c_big(){ return u2f(0x7BFF7BFFu); } // 65504

constexpr int CC = 128;                 // score: cols per block
constexpr int SCORE_PER_STREAM = 80;    // triangle chunks (32,24,16,8 per row-tile)
constexpr int NPRED_BLK = 128;          // pred: 32 full rows per block
constexpr int NSCORE_BLK = 4 * SCORE_PER_STREAM;  // 320
constexpr int NPROD = NPRED_BLK + NSCORE_BLK;     // 448 (bids 1..448)
constexpr int RTS = 1024;               // score row-tile height

// ws u32 offsets — NO initialization required for any of these:
constexpr int CTR_OFF = 0;    // monotonically growing counter (any start value OK)
constexpr int A_OFF   = 64;   // A[bid]: rank partial, bid in 1..448
constexpr int B_OFF   = 640;  // B[bid]: g2sq partial, bid in 1..128 (pred)
constexpr int C_OFF   = 832;  // C[bid]: sse partial,  bid in 1..128 (pred)

__device__ __forceinline__ void body2(unsigned lm2u, unsigned pm2u,
                                      f16x2 lk2, f16x2 rk2, float& acc){
    const f16x2 ld2 = u2f(lm2u) - lk2;
    const unsigned sgn = f2u(ld2) & 0x80008000u;
    const f16x2 pd2 = u2f(pm2u) - rk2;
    const f16x2 x2 = u2f(f2u(pd2) ^ sgn);
    const f16x2 m2 = __builtin_elementwise_max(c_two() - x2, c_zero());
    acc = fdot2(m2, c_one(), acc);
}

__device__ __forceinline__ void body2m(unsigned lm2u, unsigned pm2u,
                                       f16x2 lk2, f16x2 rk2, int d, float& acc){
    // d = (global col of low half) - (global row); include col iff col > row
    const f16x2 ld2 = u2f(lm2u) - lk2;
    const unsigned sgn = f2u(ld2) & 0x80008000u;
    const f16x2 pd2 = u2f(pm2u) - rk2;
    const f16x2 x2 = u2f(f2u(pd2) ^ sgn);
    const f16x2 m2 = __builtin_elementwise_max(c_two() - x2, c_zero());
    const unsigned mu = (d >= 0) ? ((d > 0) ? 0x3C003C00u : 0x3C000000u) : 0u;
    acc = fdot2(m2, u2f(mu), acc);
}

__device__ __forceinline__ void body2g(unsigned lm2u, unsigned pm2u,
                                       f16x2 lk2, f16x2 rk2, float& acc, float& gacc){
    const f16x2 ld2 = u2f(lm2u) - lk2;
    const unsigned sgn = f2u(ld2) & 0x80008000u;
    const f16x2 pd2 = u2f(pm2u) - rk2;
    const f16x2 x2 = u2f(f2u(pd2) ^ sgn);
    const f16x2 m2 = __builtin_elementwise_max(c_two() - x2, c_zero());
    acc = fdot2(m2, c_one(), acc);
    const f16x2 ind2 = __builtin_elementwise_min(m2 * c_big(), c_one());
    gacc = fdot2(u2f(f2u(ind2) ^ sgn), c_one(), gacc);   // +-indicator
}

__global__ __launch_bounds__(256) void fused_kernel(
    const float* __restrict__ scores, const float* __restrict__ pred,
    const float* __restrict__ label, float* __restrict__ ws,
    float* __restrict__ out)
{
    // pred: 8 col-groups x (256+4 pad) u32 per array -> conflict-free b128 reads
    __shared__ unsigned shm[2 * 2080];
    __shared__ float red[16];

    unsigned* wsu = (unsigned*)ws;
    const int bid = blockIdx.x;
    const int tid = threadIdx.x;

    // ================= finalizer block (bid 0, dispatched first) =================
    if (bid == 0) {
        if (tid == 0) {
            // snapshot BEFORE any producer can possibly finish (producers take µs)
            const unsigned snap = __hip_atomic_load(wsu + CTR_OFF, __ATOMIC_RELAXED,
                                                    SCOPE_AGENT);
            unsigned guard = 0;
            while ((__hip_atomic_load(wsu + CTR_OFF, __ATOMIC_RELAXED, SCOPE_AGENT)
                    - snap) < (unsigned)NPROD) {
                __builtin_amdgcn_s_sleep(8);
                if (++guard > (1u << 27)) break;   // safety valve: fail loud, not hang
            }
            __threadfence();   // acquire all producers' released scalar slots
        }
        __syncthreads();

        float br = 0.f, pr = 0.f, g2sq = 0.f, sse = 0.f;
        {
            const int b1 = 1 + tid;                 // 1..256
            const float a1 = __uint_as_float(__hip_atomic_load(
                wsu + A_OFF + b1, __ATOMIC_RELAXED, SCOPE_AGENT));
            if (b1 <= NPRED_BLK) pr += a1; else br += a1;
            const int b2 = 257 + tid;               // 257..512
            if (b2 <= NPROD) {
                br += __uint_as_float(__hip_atomic_load(
                    wsu + A_OFF + b2, __ATOMIC_RELAXED, SCOPE_AGENT));
            }
            if (tid < NPRED_BLK) {
                g2sq = __uint_as_float(__hip_atomic_load(
                    wsu + B_OFF + 1 + tid, __ATOMIC_RELAXED, SCOPE_AGENT));
                sse  = __uint_as_float(__hip_atomic_load(
                    wsu + C_OFF + 1 + tid, __ATOMIC_RELAXED, SCOPE_AGENT));
            }
        }
        #pragma unroll
        for (int off = 32; off > 0; off >>= 1) {
            br   += __shfl_xor(br,   off, 64);
            pr   += __shfl_xor(pr,   off, 64);
            g2sq += __shfl_xor(g2sq, off, 64);
            sse  += __shfl_xor(sse,  off, 64);
        }
        const int wid = tid >> 6;
        const int lane = tid & 63;
        if (lane == 0) {
            red[wid] = br; red[4 + wid] = pr;
            red[8 + wid] = g2sq; red[12 + wid] = sse;
        }
        __syncthreads();
        if (tid == 0) {
            const float brT   = red[0] + red[1] + red[2] + red[3];    // i<j only
            const float prT   = red[4] + red[5] + red[6] + red[7];    // full matrix
            const float g2sqT = red[8] + red[9] + red[10] + red[11];
            const float sseT  = red[12] + red[13] + red[14] + red[15];
            const float rankp = (prT - (float)N * MARGINF) * 0.5f;
            const float mse = sseT / (float)N;
            const float g1 = (2.0f / (float)N) * sqrtf(sseT);
            const float g2 = sqrtf(g2sqT);
            const float beta = g1 / (g2 + EPSF);
            out[0] = 0.25f * brT + mse + beta * rankp;
        }
        return;
    }

    // ================= producer blocks (bid 1..448) =================
    const bool isPred = (bid <= NPRED_BLK);
    float rank_total, g2sq_total = 0.f, sse_total = 0.f;

    if (isPred) {
        // ---- pred: 32 full rows, complete grad per row in-block ----
        const int rb = (bid - 1) * 32;
        // stage all 4096 cols packed fp16, swizzled: shm[q*260 + t]
        #pragma unroll
        for (int q = 0; q < 8; ++q) {
            const int j = q * 256 + tid;           // packed index 0..2047
            const float2 lf = *(const float2*)&label[2 * j];
            shm[q * 260 + tid] = pku(lf.x, lf.y);
            const float2 pf = *(const float2*)&pred[2 * j];
            shm[2080 + q * 260 + tid] = pku(pf.x, pf.y);
        }
        __syncthreads();

        const int rowofs = tid >> 3;               // 0..31
        const int cg = tid & 7;                    // col group: 512 cols each
        const int r = rb + rowofs;
        const f16x2 rk2 = pk2(pred[r]);
        const f16x2 lk2 = pk2(label[r]);
        const unsigned base = cg * 260;

        float acc0 = 0.f, acc1 = 0.f, g0 = 0.f, g1v = 0.f;
        #pragma unroll 4
        for (int it = 0; it < 64; ++it) {
            const uint4 l4 = *(const uint4*)&shm[base + it * 4];
            const uint4 s4 = *(const uint4*)&shm[2080 + base + it * 4];
            body2g(l4.x, s4.x, lk2, rk2, acc0, g0);
            body2g(l4.y, s4.y, lk2, rk2, acc1, g1v);
            body2g(l4.z, s4.z, lk2, rk2, acc0, g0);
            body2g(l4.w, s4.w, lk2, rk2, acc1, g1v);
        }
        rank_total = acc0 + acc1;
        float g = g0 + g1v;
        if (cg == (r >> 9)) g -= 1.0f;             // ref: sign(0)=0 on diagonal
        // sum g over the 8 col-groups of this row (lanes rowofs*8+cg)
        g += __shfl_xor(g, 1, 64);
        g += __shfl_xor(g, 2, 64);
        g += __shfl_xor(g, 4, 64);
        if (cg == 0) {
            g2sq_total = g * g;
            const float d = pred[r] - label[r];    // f32-exact sse
            sse_total = d * d;
        }
    } else {
        // ---- score: strict upper-triangle, 4 rows/thread (R7-proven) ----
        const int b = bid - 1 - NPRED_BLK;         // 0..319
        const int stream = b / SCORE_PER_STREAM;
        const int t = b % SCORE_PER_STREAM;
        int ti, c;
        if      (t < 32) { ti = 0; c = t; }
        else if (t < 56) { ti = 1; c = 8  + (t - 32); }
        else if (t < 72) { ti = 2; c = 16 + (t - 56); }
        else             { ti = 3; c = 24 + (t - 72); }
        const float* __restrict__ p = scores + stream * N;
        const int c0 = c * CC;
        unsigned* lab16 = shm;
        unsigned* col16 = shm + 2080;

        if (tid < CC / 2) {
            const float2 lf = *(const float2*)&label[c0 + 2 * tid];
            lab16[tid] = pku(lf.x, lf.y);
        } else if (tid < CC) {
            const int q = tid - CC / 2;
            const float2 pf = *(const float2*)&p[c0 + 2 * q];
            col16[q] = pku(pf.x, pf.y);
        }
        __syncthreads();

        const int rb = ti * RTS;
        int r[4]; f16x2 rk2[4], lk2[4];
        #pragma unroll
        for (int k = 0; k < 4; ++k) {
            r[k] = rb + tid + 256 * k;
            rk2[k] = pk2(p[r[k]]);
            lk2[k] = pk2(label[r[k]]);
        }
        float acc[8] = {0.f,0.f,0.f,0.f,0.f,0.f,0.f,0.f};

        if (c >= 8 * (ti + 1)) {
            #pragma unroll 4
            for (int q = 0; q < CC / 8; ++q) {
                const uint4 l4 = *(const uint4*)&lab16[q * 4];
                const uint4 s4 = *(const uint4*)&col16[q * 4];
                #pragma unroll
                for (int k = 0; k < 4; ++k) {
                    body2(l4.x, s4.x, lk2[k], rk2[k], acc[k]);
                    body2(l4.y, s4.y, lk2[k], rk2[k], acc[4 + k]);
                    body2(l4.z, s4.z, lk2[k], rk2[k], acc[k]);
                    body2(l4.w, s4.w, lk2[k], rk2[k], acc[4 + k]);
                }
            }
        } else {
            #pragma unroll 4
            for (int q = 0; q < CC / 8; ++q) {
                const uint4 l4 = *(const uint4*)&lab16[q * 4];
                const uint4 s4 = *(const uint4*)&col16[q * 4];
                const int cb = c0 + q * 8;
                #pragma unroll
                for (int k = 0; k < 4; ++k) {
                    body2m(l4.x, s4.x, lk2[k], rk2[k], cb + 0 - r[k], acc[k]);
                    body2m(l4.y, s4.y, lk2[k], rk2[k], cb + 2 - r[k], acc[4 + k]);
                    body2m(l4.z, s4.z, lk2[k], rk2[k], cb + 4 - r[k], acc[k]);
                    body2m(l4.w, s4.w, lk2[k], rk2[k], cb + 6 - r[k], acc[4 + k]);
                }
            }
        }
        rank_total = (acc[0] + acc[1]) + (acc[2] + acc[3])
                   + (acc[4] + acc[5]) + (acc[6] + acc[7]);
    }

    // ---- block reduce (rank always; g2sq/sse only meaningful for pred) ----
    #pragma unroll
    for (int off = 32; off > 0; off >>= 1) {
        rank_total += __shfl_xor(rank_total, off, 64);
        g2sq_total += __shfl_xor(g2sq_total, off, 64);
        sse_total  += __shfl_xor(sse_total,  off, 64);
    }
    const int wid = tid >> 6;
    const int lane = tid & 63;
    if (lane == 0) {
        red[wid] = rank_total; red[4 + wid] = g2sq_total; red[8 + wid] = sse_total;
    }
    __syncthreads();
    if (tid == 0) {
        const float rankT = red[0] + red[1] + red[2] + red[3];
        __hip_atomic_store(wsu + A_OFF + bid, __float_as_uint(rankT),
                           __ATOMIC_RELAXED, SCOPE_AGENT);
        if (isPred) {
            const float g2T  = red[4] + red[5] + red[6] + red[7];
            const float sseT = red[8] + red[9] + red[10] + red[11];
            __hip_atomic_store(wsu + B_OFF + bid, __float_as_uint(g2T),
                               __ATOMIC_RELAXED, SCOPE_AGENT);
            __hip_atomic_store(wsu + C_OFF + bid, __float_as_uint(sseT),
                               __ATOMIC_RELAXED, SCOPE_AGENT);
        }
        // publish: release RMW orders the relaxed slot stores before it
        __hip_atomic_fetch_add(wsu + CTR_OFF, 1u, __ATOMIC_RELEASE, SCOPE_AGENT);
    }
}

extern "C" void kernel_launch(void* const* d_in, const int* in_sizes, int n_in,
                              void* d_out, int out_size, void* d_ws, size_t ws_size,
                              hipStream_t stream) {
    const float* scores = (const float*)d_in[0];
    const float* pred   = (const float*)d_in[1];
    const float* label  = (const float*)d_in[2];
    float* ws  = (float*)d_ws;
    float* out = (float*)d_out;

    fused_kernel<<<NPROD + 1, 256, 0, stream>>>(scores, pred, label, ws, out);
}